// Round 2
// baseline (2883.942 us; speedup 1.0000x reference)
//
#include <hip/hip_runtime.h>

// GraphSAGE-ish: agg_mean = (scatter-add both directions)/deg; out = agg_mean@Wn + x@Ws + b
// N=50000 nodes, E=1.6M edges, DIM=128, all fp32.

constexpr int DIM = 128;
constexpr int RPB = 32;   // rows per block in GEMM

// --- Kernel 1: edge scatter with HW fp32 atomics. One 64-lane wave per edge. ---
__global__ __launch_bounds__(256) void gnn_scatter(
    const float* __restrict__ x,
    const int*   __restrict__ edge,   // [E][2] int32
    float* __restrict__ agg,          // [N][128], pre-zeroed
    float* __restrict__ deg,          // [N], pre-zeroed
    int n_edges)
{
    int wave = (blockIdx.x * blockDim.x + threadIdx.x) >> 6;
    int lane = threadIdx.x & 63;
    if (wave >= n_edges) return;

    int2 e = ((const int2*)edge)[wave];   // wave-uniform 8B load
    int si = e.x, di = e.y;

    const float2* xs = (const float2*)(x + (size_t)si * DIM);
    const float2* xd = (const float2*)(x + (size_t)di * DIM);
    float2 vs = xs[lane];   // cols 2*lane, 2*lane+1 of x[src]
    float2 vd = xd[lane];

    float* as = agg + (size_t)si * DIM + lane * 2;
    float* ad = agg + (size_t)di * DIM + lane * 2;
    unsafeAtomicAdd(as,     vd.x);
    unsafeAtomicAdd(as + 1, vd.y);
    unsafeAtomicAdd(ad,     vs.x);
    unsafeAtomicAdd(ad + 1, vs.y);

    if (lane == 0) {
        unsafeAtomicAdd(&deg[si], 1.0f);
        unsafeAtomicAdd(&deg[di], 1.0f);
    }
}

// --- Kernel 2: fused epilogue GEMM: out = (agg*invdeg)@Wn + x@Ws + b ---
// 256 threads: col j = t&31 covers {j, j+32, j+64, j+96}; row group g = t>>5 covers 4 rows.
__global__ __launch_bounds__(256) void gnn_gemm(
    const float* __restrict__ x,
    const float* __restrict__ agg,
    const float* __restrict__ deg,
    const float* __restrict__ Wn,     // [128][128] row-major (k, j)
    const float* __restrict__ Ws,
    const float* __restrict__ bias,   // [128]
    float* __restrict__ out,          // [N][128]
    int n_nodes)
{
    __shared__ float A[RPB][2 * DIM];   // [row][k]: k<128 agg_mean, k>=128 x   (32 KB)
    __shared__ float invdeg[RPB];

    int t = threadIdx.x;
    int row0 = blockIdx.x * RPB;

    if (t < RPB) {
        int n = row0 + t;
        float dg = (n < n_nodes) ? deg[n] : 1.0f;
        invdeg[t] = 1.0f / fmaxf(dg, 1.0f);
    }
    __syncthreads();

    for (int i = t; i < RPB * DIM; i += 256) {
        int r = i >> 7;
        int c = i & 127;
        int n = row0 + r;
        float am = 0.f, xv = 0.f;
        if (n < n_nodes) {
            am = agg[(size_t)n * DIM + c] * invdeg[r];
            xv = x[(size_t)n * DIM + c];
        }
        A[r][c] = am;
        A[r][c + DIM] = xv;
    }
    __syncthreads();

    int j = t & 31;
    int g = t >> 5;                  // 0..7, rows g*4..g*4+3
    float acc[4][4];
    #pragma unroll
    for (int i = 0; i < 4; i++)
        #pragma unroll
        for (int c = 0; c < 4; c++) acc[i][c] = 0.f;

    // agg_mean @ Wn
    #pragma unroll 4
    for (int k = 0; k < DIM; k++) {
        float w0 = Wn[k * DIM + j];
        float w1 = Wn[k * DIM + j + 32];
        float w2 = Wn[k * DIM + j + 64];
        float w3 = Wn[k * DIM + j + 96];
        #pragma unroll
        for (int i = 0; i < 4; i++) {
            float a = A[g * 4 + i][k];     // broadcast within wave
            acc[i][0] = fmaf(a, w0, acc[i][0]);
            acc[i][1] = fmaf(a, w1, acc[i][1]);
            acc[i][2] = fmaf(a, w2, acc[i][2]);
            acc[i][3] = fmaf(a, w3, acc[i][3]);
        }
    }
    // x @ Ws
    #pragma unroll 4
    for (int k = 0; k < DIM; k++) {
        float w0 = Ws[k * DIM + j];
        float w1 = Ws[k * DIM + j + 32];
        float w2 = Ws[k * DIM + j + 64];
        float w3 = Ws[k * DIM + j + 96];
        #pragma unroll
        for (int i = 0; i < 4; i++) {
            float a = A[g * 4 + i][k + DIM];
            acc[i][0] = fmaf(a, w0, acc[i][0]);
            acc[i][1] = fmaf(a, w1, acc[i][1]);
            acc[i][2] = fmaf(a, w2, acc[i][2]);
            acc[i][3] = fmaf(a, w3, acc[i][3]);
        }
    }

    float b0 = bias[j], b1 = bias[j + 32], b2 = bias[j + 64], b3 = bias[j + 96];
    #pragma unroll
    for (int i = 0; i < 4; i++) {
        int n = row0 + g * 4 + i;
        if (n < n_nodes) {
            float* o = out + (size_t)n * DIM + j;
            o[0]  = acc[i][0] + b0;
            o[32] = acc[i][1] + b1;
            o[64] = acc[i][2] + b2;
            o[96] = acc[i][3] + b3;
        }
    }
}

extern "C" void kernel_launch(void* const* d_in, const int* in_sizes, int n_in,
                              void* d_out, int out_size, void* d_ws, size_t ws_size,
                              hipStream_t stream) {
    const float* x    = (const float*)d_in[0];
    const int*   edge = (const int*)  d_in[1];   // int inputs arrive as int32
    const float* Wn   = (const float*)d_in[2];
    const float* Ws   = (const float*)d_in[3];
    const float* b    = (const float*)d_in[4];
    float* out = (float*)d_out;

    const int n_nodes = in_sizes[0] / DIM;   // 50000
    const int n_edges = in_sizes[1] / 2;     // 1600000

    float* agg = (float*)d_ws;                       // [N][128]
    float* deg = agg + (size_t)n_nodes * DIM;        // [N]

    // zero agg + deg (ws is poisoned 0xAA before every launch)
    hipMemsetAsync(d_ws, 0, ((size_t)n_nodes * DIM + (size_t)n_nodes) * sizeof(float), stream);

    const int scatter_blocks = (n_edges + 3) / 4;    // 4 edges (waves) per block
    gnn_scatter<<<scatter_blocks, 256, 0, stream>>>(x, edge, agg, deg, n_edges);

    const int gemm_blocks = (n_nodes + RPB - 1) / RPB;
    gnn_gemm<<<gemm_blocks, 256, 0, stream>>>(x, agg, deg, Wn, Ws, b, out, n_nodes);
}

// Round 3
// 871.130 us; speedup vs baseline: 3.3106x; 3.3106x over previous
//
#include <hip/hip_runtime.h>

// GNN mean-aggregate + dual GEMM, N=50000 nodes, E=1.6M edges, DIM=128, fp32.
// Strategy: no float atomics. Build per-node neighbor buckets (int atomics only),
// gather-sum per node at LLC bandwidth, then fused GEMM.

constexpr int DIM = 128;
constexpr int RPB = 32;

// --- K1: incidence histogram (also yields degrees) ---
__global__ __launch_bounds__(256) void k_hist(
    const int* __restrict__ edge, int* __restrict__ counts, int n_edges)
{
    int i = blockIdx.x * blockDim.x + threadIdx.x;
    if (i >= n_edges) return;
    int2 e = ((const int2*)edge)[i];
    atomicAdd(&counts[e.x], 1);
    atomicAdd(&counts[e.y], 1);
}

// --- K2: single-block exclusive scan counts[n] -> offsets[n+1]; cursor = copy ---
__global__ __launch_bounds__(1024) void k_scan(
    const int* __restrict__ counts, int* __restrict__ offsets,
    int* __restrict__ cursor, int n)
{
    __shared__ int ls[1024];
    int t = threadIdx.x;
    int chunk = (n + 1023) / 1024;
    int lo = t * chunk;
    int hi = min(lo + chunk, n);
    int sum = 0;
    for (int i = lo; i < hi; i++) sum += counts[i];
    ls[t] = sum;
    __syncthreads();
    // Hillis-Steele inclusive scan over 1024 partials
    for (int d = 1; d < 1024; d <<= 1) {
        int v = (t >= d) ? ls[t - d] : 0;
        __syncthreads();
        if (t >= d) ls[t] += v;
        __syncthreads();
    }
    int run = ls[t] - sum;   // exclusive base for this chunk
    for (int i = lo; i < hi; i++) {
        offsets[i] = run;
        cursor[i]  = run;
        run += counts[i];
    }
    if (t == 1023) offsets[n] = ls[1023];
}

// --- K3: fill neighbor buckets ---
__global__ __launch_bounds__(256) void k_fill(
    const int* __restrict__ edge, int* __restrict__ cursor,
    int* __restrict__ nbr, int n_edges)
{
    int i = blockIdx.x * blockDim.x + threadIdx.x;
    if (i >= n_edges) return;
    int2 e = ((const int2*)edge)[i];
    int p = atomicAdd(&cursor[e.x], 1);
    nbr[p] = e.y;
    int q = atomicAdd(&cursor[e.y], 1);
    nbr[q] = e.x;
}

// --- K4: gather + mean. One wave per node; lane owns cols {2*lane, 2*lane+1}. ---
// Writes agg_mean directly into `aggm` (which is d_out, used as scratch).
__global__ __launch_bounds__(256) void k_gather(
    const float* __restrict__ x, const int* __restrict__ offsets,
    const int* __restrict__ nbr, float* __restrict__ aggm, int n_nodes)
{
    int node = blockIdx.x * 4 + (threadIdx.x >> 6);
    if (node >= n_nodes) return;
    int lane = threadIdx.x & 63;
    int base = offsets[node];
    int end  = offsets[node + 1];
    int deg  = end - base;

    float ax0 = 0.f, ay0 = 0.f, ax1 = 0.f, ay1 = 0.f;
    float ax2 = 0.f, ay2 = 0.f, ax3 = 0.f, ay3 = 0.f;

    int i = base;
    for (; i + 4 <= end; i += 4) {      // 4 independent row-loads in flight
        int v0 = nbr[i], v1 = nbr[i + 1], v2 = nbr[i + 2], v3 = nbr[i + 3];
        float2 t0 = ((const float2*)(x + (size_t)v0 * DIM))[lane];
        float2 t1 = ((const float2*)(x + (size_t)v1 * DIM))[lane];
        float2 t2 = ((const float2*)(x + (size_t)v2 * DIM))[lane];
        float2 t3 = ((const float2*)(x + (size_t)v3 * DIM))[lane];
        ax0 += t0.x; ay0 += t0.y;
        ax1 += t1.x; ay1 += t1.y;
        ax2 += t2.x; ay2 += t2.y;
        ax3 += t3.x; ay3 += t3.y;
    }
    for (; i < end; i++) {
        int v = nbr[i];
        float2 tv = ((const float2*)(x + (size_t)v * DIM))[lane];
        ax0 += tv.x; ay0 += tv.y;
    }

    float inv = 1.0f / fmaxf((float)deg, 1.0f);
    float2 r;
    r.x = (ax0 + ax1 + ax2 + ax3) * inv;
    r.y = (ay0 + ay1 + ay2 + ay3) * inv;
    ((float2*)(aggm + (size_t)node * DIM))[lane] = r;
}

// --- K5: out = aggm @ Wn + x @ Ws + b.  aggm aliases out (in-place, safe:
// each block stages its own 32 rows to LDS before overwriting them). ---
__global__ __launch_bounds__(256) void gnn_gemm(
    const float* __restrict__ x,
    const float* __restrict__ Wn,     // [128][128] row-major (k, j)
    const float* __restrict__ Ws,
    const float* __restrict__ bias,
    float* out,                       // aliased: rows hold agg_mean on entry
    int n_nodes)
{
    __shared__ float A[RPB][2 * DIM];   // [row][k]: k<128 agg_mean, k>=128 x

    int t = threadIdx.x;
    int row0 = blockIdx.x * RPB;

    for (int i = t; i < RPB * DIM; i += 256) {
        int r = i >> 7;
        int c = i & 127;
        int n = row0 + r;
        float am = 0.f, xv = 0.f;
        if (n < n_nodes) {
            am = out[(size_t)n * DIM + c];
            xv = x[(size_t)n * DIM + c];
        }
        A[r][c]       = am;
        A[r][c + DIM] = xv;
    }
    __syncthreads();

    int j = t & 31;
    int g = t >> 5;                  // rows g*4..g*4+3
    float acc[4][4];
    #pragma unroll
    for (int i = 0; i < 4; i++)
        #pragma unroll
        for (int c = 0; c < 4; c++) acc[i][c] = 0.f;

    #pragma unroll 4
    for (int k = 0; k < DIM; k++) {
        float w0 = Wn[k * DIM + j];
        float w1 = Wn[k * DIM + j + 32];
        float w2 = Wn[k * DIM + j + 64];
        float w3 = Wn[k * DIM + j + 96];
        #pragma unroll
        for (int i = 0; i < 4; i++) {
            float a = A[g * 4 + i][k];
            acc[i][0] = fmaf(a, w0, acc[i][0]);
            acc[i][1] = fmaf(a, w1, acc[i][1]);
            acc[i][2] = fmaf(a, w2, acc[i][2]);
            acc[i][3] = fmaf(a, w3, acc[i][3]);
        }
    }
    #pragma unroll 4
    for (int k = 0; k < DIM; k++) {
        float w0 = Ws[k * DIM + j];
        float w1 = Ws[k * DIM + j + 32];
        float w2 = Ws[k * DIM + j + 64];
        float w3 = Ws[k * DIM + j + 96];
        #pragma unroll
        for (int i = 0; i < 4; i++) {
            float a = A[g * 4 + i][k + DIM];
            acc[i][0] = fmaf(a, w0, acc[i][0]);
            acc[i][1] = fmaf(a, w1, acc[i][1]);
            acc[i][2] = fmaf(a, w2, acc[i][2]);
            acc[i][3] = fmaf(a, w3, acc[i][3]);
        }
    }

    float b0 = bias[j], b1 = bias[j + 32], b2 = bias[j + 64], b3 = bias[j + 96];
    #pragma unroll
    for (int i = 0; i < 4; i++) {
        int n = row0 + g * 4 + i;
        if (n < n_nodes) {
            float* o = out + (size_t)n * DIM + j;
            o[0]  = acc[i][0] + b0;
            o[32] = acc[i][1] + b1;
            o[64] = acc[i][2] + b2;
            o[96] = acc[i][3] + b3;
        }
    }
}

extern "C" void kernel_launch(void* const* d_in, const int* in_sizes, int n_in,
                              void* d_out, int out_size, void* d_ws, size_t ws_size,
                              hipStream_t stream) {
    const float* x    = (const float*)d_in[0];
    const int*   edge = (const int*)  d_in[1];
    const float* Wn   = (const float*)d_in[2];
    const float* Ws   = (const float*)d_in[3];
    const float* b    = (const float*)d_in[4];
    float* out = (float*)d_out;

    const int n_nodes = in_sizes[0] / DIM;   // 50000
    const int n_edges = in_sizes[1] / 2;     // 1600000

    // Workspace layout (ints): counts[n] | offsets[n+1] | cursor[n] | nbr[2E]
    int* counts  = (int*)d_ws;
    int* offsets = counts + n_nodes;
    int* cursor  = offsets + n_nodes + 1;
    int* nbr     = cursor + n_nodes;

    // zero only counts (offsets/cursor/nbr fully overwritten each call)
    hipMemsetAsync(counts, 0, (size_t)n_nodes * sizeof(int), stream);

    const int eb = (n_edges + 255) / 256;
    k_hist<<<eb, 256, 0, stream>>>(edge, counts, n_edges);
    k_scan<<<1, 1024, 0, stream>>>(counts, offsets, cursor, n_nodes);
    k_fill<<<eb, 256, 0, stream>>>(edge, cursor, nbr, n_edges);

    const int gb = (n_nodes + 3) / 4;        // one wave per node, 4 waves/block
    k_gather<<<gb, 256, 0, stream>>>(x, offsets, nbr, out, n_nodes);

    const int mb = (n_nodes + RPB - 1) / RPB;
    gnn_gemm<<<mb, 256, 0, stream>>>(x, Wn, Ws, b, out, n_nodes);
}

// Round 4
// 360.984 us; speedup vs baseline: 7.9891x; 2.4132x over previous
//
#include <hip/hip_runtime.h>

// GNN mean-aggregate + dual GEMM. N=50000, E=1.6M, DIM=128, fp32 in/out.
// Pipeline: bucket-hist -> scan -> bin (coarse counting sort, 4B packed
// entries) -> per-bucket LDS counting sort -> bf16 gather -> fused GEMM.

constexpr int DIM   = 128;
constexpr int RPB   = 32;
constexpr int NBMAX = 512;    // max coarse buckets (node>>7); N=50000 -> 391
constexpr int EPB   = 2048;   // edges per binning block (256 thr x 8)

__device__ __forceinline__ unsigned bf16rne(float f) {
    unsigned u = __float_as_uint(f);
    return (u + 0x7FFFu + ((u >> 16) & 1u)) >> 16;
}
__device__ __forceinline__ float bf_lo(unsigned u) { return __uint_as_float(u << 16); }
__device__ __forceinline__ float bf_hi(unsigned u) { return __uint_as_float(u & 0xFFFF0000u); }

// --- K0: coarse bucket histogram (LDS-aggregated) ---
__global__ __launch_bounds__(256) void k_bhist(
    const int* __restrict__ edge, int* __restrict__ bucket_cnt,
    int n_edges, int nb)
{
    __shared__ int lh[NBMAX];
    int t = threadIdx.x;
    for (int i = t; i < nb; i += 256) lh[i] = 0;
    __syncthreads();
    int e0 = blockIdx.x * EPB;
    #pragma unroll
    for (int k = 0; k < 8; k++) {
        int idx = e0 + k * 256 + t;
        if (idx < n_edges) {
            int2 e = ((const int2*)edge)[idx];
            atomicAdd(&lh[e.x >> 7], 1);
            atomicAdd(&lh[e.y >> 7], 1);
        }
    }
    __syncthreads();
    for (int i = t; i < nb; i += 256) if (lh[i]) atomicAdd(&bucket_cnt[i], lh[i]);
}

// --- K2: scan bucket counts -> base & cursor; also offsets[N] = 2E ---
__global__ __launch_bounds__(512) void k_bscan(
    const int* __restrict__ bucket_cnt, int* __restrict__ bucket_base,
    int* __restrict__ bucket_cur, int* __restrict__ offsets,
    int nb, int n_nodes, int total)
{
    __shared__ int ls[512];
    int t = threadIdx.x;
    int v = (t < nb) ? bucket_cnt[t] : 0;
    ls[t] = v;
    __syncthreads();
    for (int d = 1; d < 512; d <<= 1) {
        int u = (t >= d) ? ls[t - d] : 0;
        __syncthreads();
        if (t >= d) ls[t] += u;
        __syncthreads();
    }
    if (t < nb) {
        int excl = ls[t] - v;
        bucket_base[t] = excl;
        bucket_cur[t]  = excl;
    }
    if (t == 0) offsets[n_nodes] = total;
}

// --- K1: bin edge endpoints into coarse buckets. One global atomic-return
// per (block,bucket) instead of per endpoint; entry = (node&127)<<17 | other.
__global__ __launch_bounds__(256) void k_bin(
    const int* __restrict__ edge, int* __restrict__ bucket_cur,
    unsigned* __restrict__ entries, int n_edges)
{
    __shared__ int lh[NBMAX];     // pass A: counts; pass B: cursors
    __shared__ int lbase[NBMAX];
    int t = threadIdx.x;
    for (int i = t; i < NBMAX; i += 256) lh[i] = 0;
    __syncthreads();
    int e0 = blockIdx.x * EPB;
    int2 ev[8];
    #pragma unroll
    for (int k = 0; k < 8; k++) {
        int idx = e0 + k * 256 + t;
        if (idx < n_edges) {
            ev[k] = ((const int2*)edge)[idx];
            atomicAdd(&lh[ev[k].x >> 7], 1);
            atomicAdd(&lh[ev[k].y >> 7], 1);
        } else {
            ev[k].x = -1;
        }
    }
    __syncthreads();
    for (int i = t; i < NBMAX; i += 256) {
        int c = lh[i];
        lbase[i] = c ? atomicAdd(&bucket_cur[i], c) : 0;
        lh[i] = 0;
    }
    __syncthreads();
    #pragma unroll
    for (int k = 0; k < 8; k++) {
        int a = ev[k].x;
        if (a < 0) continue;
        int b = ev[k].y;
        int sa = lbase[a >> 7] + atomicAdd(&lh[a >> 7], 1);
        entries[sa] = ((unsigned)(a & 127) << 17) | (unsigned)b;
        int sb = lbase[b >> 7] + atomicAdd(&lh[b >> 7], 1);
        entries[sb] = ((unsigned)(b & 127) << 17) | (unsigned)a;
    }
}

// --- K3: per-bucket counting sort with LDS cursors; emits offsets + nbr ---
__global__ __launch_bounds__(256) void k_csort(
    const unsigned* __restrict__ entries, const int* __restrict__ bucket_base,
    const int* __restrict__ bucket_cnt, int* __restrict__ offsets,
    int* __restrict__ nbr, int n_nodes)
{
    int b = blockIdx.x;
    int base = bucket_base[b];
    int cnt  = bucket_cnt[b];
    __shared__ int hist[128];
    __shared__ int scn[128];
    int t = threadIdx.x;
    if (t < 128) hist[t] = 0;
    __syncthreads();
    for (int i = t; i < cnt; i += 256)
        atomicAdd(&hist[entries[base + i] >> 17], 1);
    __syncthreads();
    if (t < 128) scn[t] = hist[t];
    __syncthreads();
    for (int d = 1; d < 128; d <<= 1) {
        int u = (t >= d && t < 128) ? scn[t - d] : 0;
        __syncthreads();
        if (t >= d && t < 128) scn[t] += u;
        __syncthreads();
    }
    if (t < 128) {
        int excl = scn[t] - hist[t];
        int node = (b << 7) + t;
        if (node < n_nodes) offsets[node] = base + excl;
        hist[t] = excl;            // reuse as cursor
    }
    __syncthreads();
    for (int i = t; i < cnt; i += 256) {
        unsigned e = entries[base + i];
        int r = e >> 17;
        int slot = base + atomicAdd(&hist[r], 1);
        nbr[slot] = (int)(e & 0x1FFFFu);
    }
}

// --- K4: x (fp32) -> xh (bf16, RNE), packed 2/uint ---
__global__ __launch_bounds__(256) void k_tobf16(
    const float* __restrict__ x, unsigned* __restrict__ xh, int n4)
{
    int i = blockIdx.x * 256 + threadIdx.x;
    if (i >= n4) return;
    float4 f = ((const float4*)x)[i];
    uint2 o;
    o.x = bf16rne(f.x) | (bf16rne(f.y) << 16);
    o.y = bf16rne(f.z) | (bf16rne(f.w) << 16);
    ((uint2*)xh)[i] = o;
}

// --- K5: gather + mean from bf16 rows. One wave per node; lane owns cols
// {2*lane, 2*lane+1} (one uint per row per lane). fp32 accumulate. ---
__global__ __launch_bounds__(256) void k_gather(
    const unsigned* __restrict__ xh, const int* __restrict__ offsets,
    const int* __restrict__ nbr, float* __restrict__ aggm, int n_nodes)
{
    int node = blockIdx.x * 4 + (threadIdx.x >> 6);
    if (node >= n_nodes) return;
    int lane = threadIdx.x & 63;
    int base = offsets[node];
    int end  = offsets[node + 1];

    float sx0 = 0.f, sy0 = 0.f, sx1 = 0.f, sy1 = 0.f;
    float sx2 = 0.f, sy2 = 0.f, sx3 = 0.f, sy3 = 0.f;

    int i = base;
    for (; i + 4 <= end; i += 4) {
        int v0 = nbr[i], v1 = nbr[i + 1], v2 = nbr[i + 2], v3 = nbr[i + 3];
        unsigned u0 = xh[v0 * 64 + lane];
        unsigned u1 = xh[v1 * 64 + lane];
        unsigned u2 = xh[v2 * 64 + lane];
        unsigned u3 = xh[v3 * 64 + lane];
        sx0 += bf_lo(u0); sy0 += bf_hi(u0);
        sx1 += bf_lo(u1); sy1 += bf_hi(u1);
        sx2 += bf_lo(u2); sy2 += bf_hi(u2);
        sx3 += bf_lo(u3); sy3 += bf_hi(u3);
    }
    for (; i < end; i++) {
        unsigned u = xh[nbr[i] * 64 + lane];
        sx0 += bf_lo(u); sy0 += bf_hi(u);
    }

    float inv = 1.0f / fmaxf((float)(end - base), 1.0f);
    float2 r;
    r.x = (sx0 + sx1 + sx2 + sx3) * inv;
    r.y = (sy0 + sy1 + sy2 + sy3) * inv;
    ((float2*)(aggm + (size_t)node * DIM))[lane] = r;
}

// --- K6: out = aggm @ Wn + x @ Ws + b ; aggm aliases out (staged to LDS) ---
__global__ __launch_bounds__(256) void gnn_gemm(
    const float* __restrict__ x,
    const float* __restrict__ Wn,
    const float* __restrict__ Ws,
    const float* __restrict__ bias,
    float* out,
    int n_nodes)
{
    __shared__ float A[RPB][2 * DIM];
    int t = threadIdx.x;
    int row0 = blockIdx.x * RPB;

    for (int i = t; i < RPB * DIM; i += 256) {
        int r = i >> 7;
        int c = i & 127;
        int n = row0 + r;
        float am = 0.f, xv = 0.f;
        if (n < n_nodes) {
            am = out[(size_t)n * DIM + c];
            xv = x[(size_t)n * DIM + c];
        }
        A[r][c]       = am;
        A[r][c + DIM] = xv;
    }
    __syncthreads();

    int j = t & 31;
    int g = t >> 5;
    float acc[4][4];
    #pragma unroll
    for (int i = 0; i < 4; i++)
        #pragma unroll
        for (int c = 0; c < 4; c++) acc[i][c] = 0.f;

    #pragma unroll 4
    for (int k = 0; k < DIM; k++) {
        float w0 = Wn[k * DIM + j];
        float w1 = Wn[k * DIM + j + 32];
        float w2 = Wn[k * DIM + j + 64];
        float w3 = Wn[k * DIM + j + 96];
        #pragma unroll
        for (int i = 0; i < 4; i++) {
            float a = A[g * 4 + i][k];
            acc[i][0] = fmaf(a, w0, acc[i][0]);
            acc[i][1] = fmaf(a, w1, acc[i][1]);
            acc[i][2] = fmaf(a, w2, acc[i][2]);
            acc[i][3] = fmaf(a, w3, acc[i][3]);
        }
    }
    #pragma unroll 4
    for (int k = 0; k < DIM; k++) {
        float w0 = Ws[k * DIM + j];
        float w1 = Ws[k * DIM + j + 32];
        float w2 = Ws[k * DIM + j + 64];
        float w3 = Ws[k * DIM + j + 96];
        #pragma unroll
        for (int i = 0; i < 4; i++) {
            float a = A[g * 4 + i][k + DIM];
            acc[i][0] = fmaf(a, w0, acc[i][0]);
            acc[i][1] = fmaf(a, w1, acc[i][1]);
            acc[i][2] = fmaf(a, w2, acc[i][2]);
            acc[i][3] = fmaf(a, w3, acc[i][3]);
        }
    }

    float b0 = bias[j], b1 = bias[j + 32], b2 = bias[j + 64], b3 = bias[j + 96];
    #pragma unroll
    for (int i = 0; i < 4; i++) {
        int n = row0 + g * 4 + i;
        if (n < n_nodes) {
            float* o = out + (size_t)n * DIM + j;
            o[0]  = acc[i][0] + b0;
            o[32] = acc[i][1] + b1;
            o[64] = acc[i][2] + b2;
            o[96] = acc[i][3] + b3;
        }
    }
}

extern "C" void kernel_launch(void* const* d_in, const int* in_sizes, int n_in,
                              void* d_out, int out_size, void* d_ws, size_t ws_size,
                              hipStream_t stream) {
    const float* x    = (const float*)d_in[0];
    const int*   edge = (const int*)  d_in[1];
    const float* Wn   = (const float*)d_in[2];
    const float* Ws   = (const float*)d_in[3];
    const float* b    = (const float*)d_in[4];
    float* out = (float*)d_out;

    const int n_nodes = in_sizes[0] / DIM;   // 50000
    const int n_edges = in_sizes[1] / 2;     // 1600000
    const int nb = (n_nodes + 127) >> 7;     // 391 coarse buckets
    const int total = 2 * n_edges;

    // ws layout (ints): entries[2E] | nbr[2E] | offsets[N+1] | cnt[nb] | base[nb] | cur[nb]
    // xh (bf16 x, N*64 uints = 2E uints) aliases entries after k_csort.
    unsigned* entries   = (unsigned*)d_ws;
    int* nbr            = (int*)d_ws + total;
    int* offsets        = nbr + total;
    int* bucket_cnt     = offsets + n_nodes + 1;
    int* bucket_base    = bucket_cnt + nb;
    int* bucket_cur     = bucket_base + nb;
    unsigned* xh        = entries;

    hipMemsetAsync(bucket_cnt, 0, (size_t)nb * sizeof(int), stream);

    const int bb = (n_edges + EPB - 1) / EPB;   // 782
    k_bhist<<<bb, 256, 0, stream>>>(edge, bucket_cnt, n_edges, nb);
    k_bscan<<<1, 512, 0, stream>>>(bucket_cnt, bucket_base, bucket_cur,
                                   offsets, nb, n_nodes, total);
    k_bin<<<bb, 256, 0, stream>>>(edge, bucket_cur, entries, n_edges);
    k_csort<<<nb, 256, 0, stream>>>(entries, bucket_base, bucket_cnt,
                                    offsets, nbr, n_nodes);

    const int n4 = n_nodes * DIM / 4;
    k_tobf16<<<(n4 + 255) / 256, 256, 0, stream>>>(x, xh, n4);

    k_gather<<<(n_nodes + 3) / 4, 256, 0, stream>>>(xh, offsets, nbr, out, n_nodes);

    gnn_gemm<<<(n_nodes + RPB - 1) / RPB, 256, 0, stream>>>(x, Wn, Ws, b, out, n_nodes);
}